// Round 1
// baseline (497.693 us; speedup 1.0000x reference)
//
#include <hip/hip_runtime.h>
#include <hip/hip_fp16.h>

#define DI __device__ __forceinline__

typedef __attribute__((ext_vector_type(4))) float f32x4;
typedef __attribute__((ext_vector_type(8))) short s16x8;

DI unsigned short f2h(float f) { __half h = __float2half(f); return __half_as_ushort(h); }
DI float h2f(unsigned short u) { return __half2float(__ushort_as_half(u)); }

DI void gload16(const void* g, void* l) {
    __builtin_amdgcn_global_load_lds((const __attribute__((address_space(1))) void*)g,
                                     (__attribute__((address_space(3))) void*)l, 16, 0, 0);
}

// ---------------------------------------------------------------------------
// Weight prep: w[k][o][i] = f16( v[k][o][i] * g[k][o]/||v[k][o]|| * (scale_k if use_scale) )
// bias[k][o]  = b[k][o] * (scale_k if use_scale);  scale_k = relu(adj[k][k])
// One wave per (k,o) row.
// ---------------------------------------------------------------------------
template <int CIN, int CINPAD>
__global__ __launch_bounds__(256) void prep_w_kernel(
    const float* __restrict__ v, const float* __restrict__ g, const float* __restrict__ b,
    const float* __restrict__ adj, int cout, int use_scale,
    unsigned short* __restrict__ wout, float* __restrict__ biasout)
{
    const int ridx = blockIdx.x * 4 + (threadIdx.x >> 6);
    const int lane = threadIdx.x & 63;
    if (ridx >= 80 * cout) return;
    const int k = ridx / cout;
    const float* vr = v + (size_t)ridx * CIN;
    float ss = 0.f;
    for (int i = lane; i < CIN; i += 64) { float x = vr[i]; ss += x * x; }
    for (int off = 32; off >= 1; off >>= 1) ss += __shfl_xor(ss, off, 64);
    float s = g[ridx] / sqrtf(ss);
    float bias = b[ridx];
    if (use_scale) {
        float d = adj[k * 81];          // adj[k][k]
        d = d > 0.f ? d : 0.f;
        s *= d; bias *= d;
    }
    if (lane == 0) biasout[ridx] = bias;
    unsigned short* wr = wout + (size_t)ridx * CINPAD;
    for (int i = lane; i < CINPAD; i += 64) {
        float val = (i < CIN) ? vr[i] * s : 0.f;
        wr[i] = f2h(val);
    }
}

// Layer-4 weights stay f32 (tiny).
__global__ __launch_bounds__(256) void prep_w4_kernel(
    const float* __restrict__ v, const float* __restrict__ g, const float* __restrict__ b,
    float* __restrict__ wout, float* __restrict__ biasout)
{
    const int ridx = blockIdx.x * 4 + (threadIdx.x >> 6);   // 480 rows
    const int lane = threadIdx.x & 63;
    if (ridx >= 480) return;
    const float* vr = v + (size_t)ridx * 64;
    float x = vr[lane];
    float ss = x * x;
    for (int off = 32; off >= 1; off >>= 1) ss += __shfl_xor(ss, off, 64);
    float s = g[ridx] / sqrtf(ss);
    if (lane == 0) biasout[ridx] = b[ridx];
    wout[(size_t)ridx * 64 + lane] = x * s;
}

// ---------------------------------------------------------------------------
// RFF + add: h0[row][c] = f16( pf[row][c] + (c<240 ? cos(2pi*dot_c) : sin(2pi*dot_{c-240})) )
// padded to 512 channels with zeros. One wave per row (=b*80+k), 8 ch/lane.
// ---------------------------------------------------------------------------
__global__ __launch_bounds__(256) void rff_h0_kernel(
    const float* __restrict__ qp, const float* __restrict__ pf,
    const float* __restrict__ Brff, unsigned short* __restrict__ h0)
{
    const int row  = blockIdx.x * 4 + (threadIdx.x >> 6);
    const int lane = threadIdx.x & 63;
    const int c0   = lane * 8;
    const float q0 = qp[row * 3 + 0], q1 = qp[row * 3 + 1], q2 = qp[row * 3 + 2];
    unsigned short o[8];
    if (c0 < 480) {
        const bool issin = (c0 >= 240);
        const int  j0    = issin ? (c0 - 240) : c0;
        #pragma unroll
        for (int e = 0; e < 8; e++) {
            const int j = j0 + e;
            float rev = q0 * Brff[j] + q1 * Brff[240 + j] + q2 * Brff[480 + j];
            rev -= floorf(rev);                       // v_sin/v_cos take revolutions
            float t = issin ? __builtin_amdgcn_sinf(rev) : __builtin_amdgcn_cosf(rev);
            float val = pf[(size_t)row * 480 + c0 + e] + t;
            o[e] = f2h(val);
        }
    } else {
        #pragma unroll
        for (int e = 0; e < 8; e++) o[e] = 0;
    }
    *reinterpret_cast<s16x8*>(&h0[(size_t)row * 512 + c0]) =
        *reinterpret_cast<const s16x8*>(o);
}

// ---------------------------------------------------------------------------
// Per-joint GEMM layer: Y[b*80+kj][n] = leaky( sum_i X[b*80+kj][i] * W[kj][n][i] + Bias[kj][n] )
// m97 structure: 128x128 tile, BK=64, global_load_lds(16B) with pre-swizzled
// source; ds_read uses the same XOR swizzle (chunk ^= row&7).
// 4 waves in 2x2, each 64x(BN/2), mfma 16x16x32 f16 via inline asm.
// ---------------------------------------------------------------------------
template <int CIN, int COUT, int BM, int BN>
__global__ __launch_bounds__(256) void gemm_layer_kernel(
    const unsigned short* __restrict__ X, const unsigned short* __restrict__ W,
    const float* __restrict__ Bias, unsigned short* __restrict__ Y)
{
    constexpr int BK = 64;
    constexpr int WR = 2, WC = 2;
    constexpr int WM = BM / WR, WN = BN / WC;
    constexpr int FM = WM / 16, FN = WN / 16;
    __shared__ __align__(16) unsigned short sA[BM * BK];
    __shared__ __align__(16) unsigned short sB[BN * BK];
    const int tid  = threadIdx.x;
    const int wave = tid >> 6, lane = tid & 63;
    const int mt = blockIdx.x, nt = blockIdx.y, kj = blockIdx.z;
    const int m0 = mt * BM, n0 = nt * BN;
    const size_t xstride = (size_t)80 * CIN;
    const unsigned short* Ab = X + (size_t)kj * CIN;
    const unsigned short* Bb = W + (size_t)kj * COUT * CIN;
    const int wr = wave >> 1, wc = wave & 1;

    f32x4 acc[FM][FN] = {};

    constexpr int APW = (BM * 8) / 256;   // global_load_lds instrs per wave for A
    constexpr int BPW = (BN * 8) / 256;

    for (int kt = 0; kt < CIN / BK; ++kt) {
        #pragma unroll
        for (int i = 0; i < APW; i++) {
            const int cbase = (wave * APW + i) * 64;
            const int chunk = cbase + lane;
            const int row = chunk >> 3, cc = chunk & 7;
            const int sc = cc ^ (row & 7);            // inverse-swizzled source
            gload16(Ab + (size_t)(m0 + row) * xstride + (size_t)kt * BK + sc * 8,
                    sA + (size_t)cbase * 8);
        }
        #pragma unroll
        for (int i = 0; i < BPW; i++) {
            const int cbase = (wave * BPW + i) * 64;
            const int chunk = cbase + lane;
            const int row = chunk >> 3, cc = chunk & 7;
            const int sc = cc ^ (row & 7);
            gload16(Bb + (size_t)(n0 + row) * CIN + (size_t)kt * BK + sc * 8,
                    sB + (size_t)cbase * 8);
        }
        __syncthreads();
        #pragma unroll
        for (int kk = 0; kk < 2; kk++) {
            s16x8 af[FM], bf[FN];
            #pragma unroll
            for (int mf = 0; mf < FM; mf++) {
                const int row = wr * WM + mf * 16 + (lane & 15);
                const int c   = kk * 4 + (lane >> 4);
                const int sc2 = c ^ (row & 7);        // swizzled read
                af[mf] = *reinterpret_cast<const s16x8*>(&sA[row * BK + sc2 * 8]);
            }
            #pragma unroll
            for (int nf = 0; nf < FN; nf++) {
                const int row = wc * WN + nf * 16 + (lane & 15);
                const int c   = kk * 4 + (lane >> 4);
                const int sc2 = c ^ (row & 7);
                bf[nf] = *reinterpret_cast<const s16x8*>(&sB[row * BK + sc2 * 8]);
            }
            #pragma unroll
            for (int mf = 0; mf < FM; mf++)
                #pragma unroll
                for (int nf = 0; nf < FN; nf++)
                    asm("v_mfma_f32_16x16x32_f16 %0, %1, %2, %0"
                        : "+v"(acc[mf][nf]) : "v"(af[mf]), "v"(bf[nf]));
        }
        __syncthreads();
    }
    asm volatile("s_nop 7\n\ts_nop 7" :::);           // MFMA->VALU read hazard cover
    // epilogue: bias + leaky, store f16
    #pragma unroll
    for (int nf = 0; nf < FN; nf++) {
        const int n = n0 + wc * WN + nf * 16 + (lane & 15);
        const float bias = Bias[kj * COUT + n];
        #pragma unroll
        for (int mf = 0; mf < FM; mf++) {
            #pragma unroll
            for (int r = 0; r < 4; r++) {
                const int m = m0 + wr * WM + mf * 16 + (lane >> 4) * 4 + r;
                float z = acc[mf][nf][r] + bias;
                z = (z >= 0.f) ? z : 0.01f * z;
                Y[((size_t)m * 80 + kj) * COUT + n] = f2h(z);
            }
        }
    }
}

// ---------------------------------------------------------------------------
// Final layer: out[row][o] = sum_i h4[row][i]*w4[k][o][i] + b4[k][o], f32 out.
// ---------------------------------------------------------------------------
__global__ __launch_bounds__(256) void final_kernel(
    const unsigned short* __restrict__ X, const float* __restrict__ W4,
    const float* __restrict__ B4, float* __restrict__ out)
{
    const int row = blockIdx.x * 256 + threadIdx.x;
    const int k = row % 80;
    const unsigned short* x = X + (size_t)row * 64;
    float xv[64];
    #pragma unroll
    for (int i = 0; i < 8; i++) {
        s16x8 v = *reinterpret_cast<const s16x8*>(&x[i * 8]);
        #pragma unroll
        for (int e = 0; e < 8; e++) xv[i * 8 + e] = h2f((unsigned short)v[e]);
    }
    const float* w = W4 + k * 384;
    #pragma unroll
    for (int o = 0; o < 6; o++) {
        float sum = B4[k * 6 + o];
        #pragma unroll
        for (int i = 0; i < 64; i++) sum += xv[i] * w[o * 64 + i];
        out[(size_t)row * 6 + o] = sum;
    }
}

// ---------------------------------------------------------------------------
extern "C" void kernel_launch(void* const* d_in, const int* in_sizes, int n_in,
                              void* d_out, int out_size, void* d_ws, size_t ws_size,
                              hipStream_t stream)
{
    (void)in_sizes; (void)n_in; (void)out_size; (void)ws_size;
    const float* qp   = (const float*)d_in[0];
    const float* pf   = (const float*)d_in[1];
    const float* adj  = (const float*)d_in[2];
    const float* Brff = (const float*)d_in[3];
    const float* v0 = (const float*)d_in[4],  *g0 = (const float*)d_in[5],  *b0 = (const float*)d_in[6];
    const float* v1 = (const float*)d_in[7],  *g1 = (const float*)d_in[8],  *b1 = (const float*)d_in[9];
    const float* v2 = (const float*)d_in[10], *g2 = (const float*)d_in[11], *b2 = (const float*)d_in[12];
    const float* v3 = (const float*)d_in[13], *g3 = (const float*)d_in[14], *b3 = (const float*)d_in[15];
    const float* v4 = (const float*)d_in[16], *g4 = (const float*)d_in[17], *b4 = (const float*)d_in[18];
    float* out = (float*)d_out;

    char* ws = (char*)d_ws;
    size_t off = 0;
    auto alloc = [&](size_t n) -> void* {
        off = (off + 255) & ~(size_t)255;
        void* p = ws + off;
        off += n;
        return p;
    };
    unsigned short* w0 = (unsigned short*)alloc(80ull * 512 * 512 * 2);
    unsigned short* w1 = (unsigned short*)alloc(80ull * 256 * 512 * 2);
    unsigned short* w2 = (unsigned short*)alloc(80ull * 128 * 256 * 2);
    unsigned short* w3 = (unsigned short*)alloc(80ull * 64 * 128 * 2);
    float* w4    = (float*)alloc(80ull * 6 * 64 * 4);
    float* bias0 = (float*)alloc(80ull * 512 * 4);
    float* bias1 = (float*)alloc(80ull * 256 * 4);
    float* bias2 = (float*)alloc(80ull * 128 * 4);
    float* bias3 = (float*)alloc(80ull * 64 * 4);
    float* bias4 = (float*)alloc(80ull * 6 * 4);
    unsigned short* hA = (unsigned short*)alloc(163840ull * 512 * 2);
    unsigned short* hB = (unsigned short*)alloc(163840ull * 512 * 2);

    prep_w_kernel<480, 512><<<dim3(10240), 256, 0, stream>>>(v0, g0, b0, adj, 512, 1, w0, bias0);
    prep_w_kernel<512, 512><<<dim3(5120),  256, 0, stream>>>(v1, g1, b1, adj, 256, 1, w1, bias1);
    prep_w_kernel<256, 256><<<dim3(2560),  256, 0, stream>>>(v2, g2, b2, adj, 128, 1, w2, bias2);
    prep_w_kernel<128, 128><<<dim3(1280),  256, 0, stream>>>(v3, g3, b3, adj,  64, 0, w3, bias3);
    prep_w4_kernel<<<120, 256, 0, stream>>>(v4, g4, b4, w4, bias4);
    rff_h0_kernel<<<40960, 256, 0, stream>>>(qp, pf, Brff, hA);

    gemm_layer_kernel<512, 512, 128, 128><<<dim3(16, 4, 80), 256, 0, stream>>>(hA, w0, bias0, hB);
    gemm_layer_kernel<512, 256, 128, 128><<<dim3(16, 2, 80), 256, 0, stream>>>(hB, w1, bias1, hA);
    gemm_layer_kernel<256, 128, 128, 128><<<dim3(16, 1, 80), 256, 0, stream>>>(hA, w2, bias2, hB);
    gemm_layer_kernel<128,  64, 128,  64><<<dim3(16, 1, 80), 256, 0, stream>>>(hB, w3, bias3, hA);
    final_kernel<<<640, 256, 0, stream>>>(hA, w4, bias4, out);
}

// Round 3
// 376.554 us; speedup vs baseline: 1.3217x; 1.3217x over previous
//
#include <hip/hip_runtime.h>
#include <hip/hip_fp16.h>

#define DI __device__ __forceinline__

typedef __attribute__((ext_vector_type(4))) float f32x4;
typedef __attribute__((ext_vector_type(8))) short s16x8;

DI unsigned short f2h(float f) { return __half_as_ushort(__float2half(f)); }
DI float h2f(unsigned short u) { return __half2float(__ushort_as_half(u)); }

DI void gload16(const void* g, void* l) {
    __builtin_amdgcn_global_load_lds((const __attribute__((address_space(1))) void*)g,
                                     (__attribute__((address_space(3))) void*)l, 16, 0, 0);
}

// ---------------------------------------------------------------------------
// Fused prep (weight-norm fold + scale fold) + RFF encode, one mega-launch.
// Block ranges select the job; one wave per output row.
// ---------------------------------------------------------------------------
struct PrepArgs {
    const float *qp, *pf, *adj, *Brff;
    const float *v0, *g0, *b0, *v1, *g1, *b1, *v2, *g2, *b2, *v3, *g3, *b3, *v4, *g4, *b4;
    unsigned short *w0, *w1, *w2, *w3;
    float *w4;
    float *bias0, *bias1, *bias2, *bias3, *bias4;
    unsigned short *h0;
};

template <int CIN, int CINPAD>
DI void prep_row(const float* __restrict__ v, const float* __restrict__ g,
                 const float* __restrict__ b, const float* __restrict__ adj,
                 int cout, int use_scale,
                 unsigned short* __restrict__ wout, float* __restrict__ biasout,
                 int ridx, int lane)
{
    const int k = ridx / cout;
    const float* vr = v + (size_t)ridx * CIN;
    constexpr int NV = CINPAD / 64;
    float xv[NV];
    #pragma unroll
    for (int i = 0; i < NV; i++) {
        const int idx = lane + i * 64;
        xv[i] = (CIN == CINPAD || idx < CIN) ? vr[idx] : 0.f;   // guard OOB for 480-pad
    }
    float ss = 0.f;
    #pragma unroll
    for (int i = 0; i < NV; i++) ss += xv[i] * xv[i];
    #pragma unroll
    for (int off = 32; off >= 1; off >>= 1) ss += __shfl_xor(ss, off, 64);
    float s = g[ridx] / sqrtf(ss);
    float bias = b[ridx];
    if (use_scale) {
        float d = adj[k * 81];            // adj[k][k]
        d = d > 0.f ? d : 0.f;
        s *= d; bias *= d;                // leaky(z)*s == leaky(z*s), s>=0
    }
    if (lane == 0) biasout[ridx] = bias;
    unsigned short* wr = wout + (size_t)ridx * CINPAD;
    #pragma unroll
    for (int i = 0; i < NV; i++) wr[lane + i * 64] = f2h(xv[i] * s);
}

DI void prep_w4_row(const float* __restrict__ v, const float* __restrict__ g,
                    const float* __restrict__ b, float* __restrict__ wout,
                    float* __restrict__ biasout, int ridx, int lane)
{
    const float x = v[(size_t)ridx * 64 + lane];
    float ss = x * x;
    #pragma unroll
    for (int off = 32; off >= 1; off >>= 1) ss += __shfl_xor(ss, off, 64);
    const float s = g[ridx] / sqrtf(ss);
    if (lane == 0) biasout[ridx] = b[ridx];
    wout[(size_t)ridx * 64 + lane] = x * s;
}

// h0 written joint-major: h0[(kj*2048 + b)*512 + c], zero-padded 480->512
DI void rff_row(const float* __restrict__ qp, const float* __restrict__ pf,
                const float* __restrict__ Brff, unsigned short* __restrict__ h0,
                int row, int lane)
{
    const int c0 = lane * 8;
    const int bb = row / 80;
    const int kj = row - bb * 80;
    unsigned short o[8];
    if (c0 < 480) {
        const float q0 = qp[row * 3 + 0], q1 = qp[row * 3 + 1], q2 = qp[row * 3 + 2];
        float pv[8];
        *reinterpret_cast<float4*>(&pv[0]) = *reinterpret_cast<const float4*>(&pf[(size_t)row * 480 + c0]);
        *reinterpret_cast<float4*>(&pv[4]) = *reinterpret_cast<const float4*>(&pf[(size_t)row * 480 + c0 + 4]);
        const bool issin = (c0 >= 240);
        const int j0 = issin ? (c0 - 240) : c0;
        #pragma unroll
        for (int e = 0; e < 8; e++) {
            const int j = j0 + e;
            float rev = q0 * Brff[j] + q1 * Brff[240 + j] + q2 * Brff[480 + j];
            rev -= floorf(rev);           // v_sin/v_cos take revolutions
            float t = issin ? __builtin_amdgcn_sinf(rev) : __builtin_amdgcn_cosf(rev);
            o[e] = f2h(pv[e] + t);
        }
    } else {
        #pragma unroll
        for (int e = 0; e < 8; e++) o[e] = 0;
    }
    *reinterpret_cast<s16x8*>(&h0[((size_t)kj * 2048 + bb) * 512 + c0]) =
        *reinterpret_cast<const s16x8*>(o);
}

__global__ __launch_bounds__(256) void prep_rff_kernel(PrepArgs a)
{
    const int bid  = blockIdx.x;
    const int wave = threadIdx.x >> 6, lane = threadIdx.x & 63;
    if (bid < 10240)      prep_row<480, 512>(a.v0, a.g0, a.b0, a.adj, 512, 1, a.w0, a.bias0, bid * 4 + wave, lane);
    else if (bid < 15360) prep_row<512, 512>(a.v1, a.g1, a.b1, a.adj, 256, 1, a.w1, a.bias1, (bid - 10240) * 4 + wave, lane);
    else if (bid < 17920) prep_row<256, 256>(a.v2, a.g2, a.b2, a.adj, 128, 1, a.w2, a.bias2, (bid - 15360) * 4 + wave, lane);
    else if (bid < 19200) prep_row<128, 128>(a.v3, a.g3, a.b3, a.adj,  64, 0, a.w3, a.bias3, (bid - 17920) * 4 + wave, lane);
    else if (bid < 19320) prep_w4_row(a.v4, a.g4, a.b4, a.w4, a.bias4, (bid - 19200) * 4 + wave, lane);
    else                  rff_row(a.qp, a.pf, a.Brff, a.h0, (bid - 19320) * 4 + wave, lane);
}

// ---------------------------------------------------------------------------
// Per-joint GEMM. Activations joint-major [kj][2048][CIN]. Flattened 1D grid
// with T1 chunked XCD swizzle: each joint runs entirely on one XCD so A/W
// panels stay L2-resident. m97 structure: 128-tile, BK=64, global_load_lds 16B
// with pre-swizzled source + XOR-swizzled ds_read, mfma 16x16x32 f16.
// ---------------------------------------------------------------------------
template <int CIN, int COUT, int BM, int BN>
__global__ __launch_bounds__(256) void gemm_layer_kernel(
    const unsigned short* __restrict__ X, const unsigned short* __restrict__ W,
    const float* __restrict__ Bias, unsigned short* __restrict__ Y)
{
    constexpr int BK = 64;
    constexpr int MT = 2048 / BM, NT = COUT / BN;
    constexpr int NWG = MT * NT * 80;
    const int bid = blockIdx.x;
    const int swz = (bid & 7) * (NWG >> 3) + (bid >> 3);   // NWG % 8 == 0
    const int nt = swz % NT;                                // nt fastest: share A-panel
    const int mt = (swz / NT) % MT;
    const int kj = swz / (NT * MT);
    constexpr int WR = 2, WC = 2;
    constexpr int WM = BM / WR, WN = BN / WC;
    constexpr int FM = WM / 16, FN = WN / 16;
    __shared__ __align__(16) unsigned short sA[BM * BK];
    __shared__ __align__(16) unsigned short sB[BN * BK];
    const int tid = threadIdx.x, wave = tid >> 6, lane = tid & 63;
    const int m0 = mt * BM, n0 = nt * BN;
    const unsigned short* Ab = X + (size_t)kj * 2048 * CIN;
    const unsigned short* Bb = W + (size_t)kj * COUT * CIN;
    const int wr = wave >> 1, wc = wave & 1;
    f32x4 acc[FM][FN] = {};
    constexpr int APW = (BM * 8) / 256;
    constexpr int BPW = (BN * 8) / 256;

    for (int kt = 0; kt < CIN / BK; ++kt) {
        #pragma unroll
        for (int i = 0; i < APW; i++) {
            const int cbase = (wave * APW + i) * 64;
            const int chunk = cbase + lane;
            const int row = chunk >> 3, cc = chunk & 7;
            const int sc = cc ^ (row & 7);                 // inverse-swizzled source
            gload16(Ab + (size_t)(m0 + row) * CIN + kt * BK + sc * 8,
                    sA + (size_t)cbase * 8);
        }
        #pragma unroll
        for (int i = 0; i < BPW; i++) {
            const int cbase = (wave * BPW + i) * 64;
            const int chunk = cbase + lane;
            const int row = chunk >> 3, cc = chunk & 7;
            const int sc = cc ^ (row & 7);
            gload16(Bb + (size_t)(n0 + row) * CIN + kt * BK + sc * 8,
                    sB + (size_t)cbase * 8);
        }
        __syncthreads();
        #pragma unroll
        for (int kk = 0; kk < 2; kk++) {
            s16x8 af[FM], bf[FN];
            #pragma unroll
            for (int mf = 0; mf < FM; mf++) {
                const int row = wr * WM + mf * 16 + (lane & 15);
                const int c   = kk * 4 + (lane >> 4);
                const int sc2 = c ^ (row & 7);             // swizzled read
                af[mf] = *reinterpret_cast<const s16x8*>(&sA[row * BK + sc2 * 8]);
            }
            #pragma unroll
            for (int nf = 0; nf < FN; nf++) {
                const int row = wc * WN + nf * 16 + (lane & 15);
                const int c   = kk * 4 + (lane >> 4);
                const int sc2 = c ^ (row & 7);
                bf[nf] = *reinterpret_cast<const s16x8*>(&sB[row * BK + sc2 * 8]);
            }
            #pragma unroll
            for (int mf = 0; mf < FM; mf++)
                #pragma unroll
                for (int nf = 0; nf < FN; nf++)
                    asm("v_mfma_f32_16x16x32_f16 %0, %1, %2, %0"
                        : "+v"(acc[mf][nf]) : "v"(af[mf]), "v"(bf[nf]));
        }
        __syncthreads();
    }
    asm volatile("s_nop 7\n\ts_nop 7" :::);
    #pragma unroll
    for (int nf = 0; nf < FN; nf++) {
        const int n = n0 + wc * WN + nf * 16 + (lane & 15);
        const float bias = Bias[kj * COUT + n];
        #pragma unroll
        for (int mf = 0; mf < FM; mf++) {
            #pragma unroll
            for (int r = 0; r < 4; r++) {
                const int m = m0 + wr * WM + mf * 16 + (lane >> 4) * 4 + r;
                float z = acc[mf][nf][r] + bias;
                z = (z >= 0.f) ? z : 0.01f * z;
                Y[((size_t)kj * 2048 + m) * COUT + n] = f2h(z);
            }
        }
    }
}

// ---------------------------------------------------------------------------
// Tail: layer-3 GEMM (128->64) with fused layer-4 (64->6) and output store.
// h4 tile staged in LDS (XOR-chunk swizzle so per-row reads spread banks).
// ---------------------------------------------------------------------------
__global__ __launch_bounds__(256) void gemm_tail_kernel(
    const unsigned short* __restrict__ X, const unsigned short* __restrict__ W,
    const float* __restrict__ Bias, const float* __restrict__ W4,
    const float* __restrict__ B4, float* __restrict__ out)
{
    constexpr int CIN = 128, COUT = 64, BM = 128, BN = 64, BK = 64;
    constexpr int MT = 16, NWG = MT * 80;
    __shared__ __align__(16) unsigned short sA[BM * BK];   // reused as h4 tile [128][64]
    __shared__ __align__(16) unsigned short sB[BN * BK];
    __shared__ float sW4[6 * 64];
    __shared__ float sB4[6];
    const int tid = threadIdx.x, wave = tid >> 6, lane = tid & 63;
    const int bid = blockIdx.x;
    const int swz = (bid & 7) * (NWG >> 3) + (bid >> 3);
    const int mt = swz & (MT - 1);
    const int kj = swz >> 4;
    const int m0 = mt * BM;
    for (int i = tid; i < 390; i += 256) {
        if (i < 384) sW4[i] = W4[kj * 384 + i];
        else         sB4[i - 384] = B4[kj * 6 + (i - 384)];
    }
    const unsigned short* Ab = X + (size_t)kj * 2048 * CIN;
    const unsigned short* Bb = W + (size_t)kj * COUT * CIN;
    const int wr = wave >> 1, wc = wave & 1;
    constexpr int WM = 64, WN = 32, FM = 4, FN = 2;
    f32x4 acc[FM][FN] = {};
    constexpr int APW = (BM * 8) / 256;   // 4
    constexpr int BPW = (BN * 8) / 256;   // 2

    for (int kt = 0; kt < CIN / BK; ++kt) {
        #pragma unroll
        for (int i = 0; i < APW; i++) {
            const int cbase = (wave * APW + i) * 64;
            const int chunk = cbase + lane;
            const int row = chunk >> 3, cc = chunk & 7;
            const int sc = cc ^ (row & 7);
            gload16(Ab + (size_t)(m0 + row) * CIN + kt * BK + sc * 8,
                    sA + (size_t)cbase * 8);
        }
        #pragma unroll
        for (int i = 0; i < BPW; i++) {
            const int cbase = (wave * BPW + i) * 64;
            const int chunk = cbase + lane;
            const int row = chunk >> 3, cc = chunk & 7;
            const int sc = cc ^ (row & 7);
            gload16(Bb + (size_t)row * CIN + kt * BK + sc * 8,   // n0 == 0 in tail
                    sB + (size_t)cbase * 8);
        }
        __syncthreads();
        #pragma unroll
        for (int kk = 0; kk < 2; kk++) {
            s16x8 af[FM], bf[FN];
            #pragma unroll
            for (int mf = 0; mf < FM; mf++) {
                const int row = wr * WM + mf * 16 + (lane & 15);
                const int c   = kk * 4 + (lane >> 4);
                const int sc2 = c ^ (row & 7);
                af[mf] = *reinterpret_cast<const s16x8*>(&sA[row * BK + sc2 * 8]);
            }
            #pragma unroll
            for (int nf = 0; nf < FN; nf++) {
                const int row = wc * WN + nf * 16 + (lane & 15);
                const int c   = kk * 4 + (lane >> 4);
                const int sc2 = c ^ (row & 7);
                bf[nf] = *reinterpret_cast<const s16x8*>(&sB[row * BK + sc2 * 8]);
            }
            #pragma unroll
            for (int mf = 0; mf < FM; mf++)
                #pragma unroll
                for (int nf = 0; nf < FN; nf++)
                    asm("v_mfma_f32_16x16x32_f16 %0, %1, %2, %0"
                        : "+v"(acc[mf][nf]) : "v"(af[mf]), "v"(bf[nf]));
        }
        __syncthreads();
    }
    asm volatile("s_nop 7\n\ts_nop 7" :::);
    // h4 (bias+leaky) -> LDS tile, chunk-swizzled: logical chunk j at j^(row&7)
    #pragma unroll
    for (int nf = 0; nf < FN; nf++) {
        const int n = wc * WN + nf * 16 + (lane & 15);
        const float bias = Bias[kj * COUT + n];
        #pragma unroll
        for (int mf = 0; mf < FM; mf++) {
            #pragma unroll
            for (int r = 0; r < 4; r++) {
                const int rl = wr * WM + mf * 16 + (lane >> 4) * 4 + r;
                float z = acc[mf][nf][r] + bias;
                z = (z >= 0.f) ? z : 0.01f * z;
                sA[rl * 64 + (((n >> 3) ^ (rl & 7)) << 3) + (n & 7)] = f2h(z);
            }
        }
    }
    __syncthreads();
    // fused layer 4: one thread per row, 6 outputs
    if (tid < 128) {
        const int row = tid;
        float xv[64];
        #pragma unroll
        for (int j = 0; j < 8; j++) {
            s16x8 vv = *reinterpret_cast<const s16x8*>(&sA[row * 64 + ((j ^ (row & 7)) << 3)]);
            #pragma unroll
            for (int e = 0; e < 8; e++) xv[j * 8 + e] = h2f((unsigned short)vv[e]);
        }
        float* op = out + ((size_t)(m0 + row) * 80 + kj) * 6;
        #pragma unroll
        for (int o = 0; o < 6; o++) {
            float sum = sB4[o];
            #pragma unroll
            for (int i = 0; i < 64; i++) sum = fmaf(xv[i], sW4[o * 64 + i], sum);
            op[o] = sum;
        }
    }
}

// ---------------------------------------------------------------------------
extern "C" void kernel_launch(void* const* d_in, const int* in_sizes, int n_in,
                              void* d_out, int out_size, void* d_ws, size_t ws_size,
                              hipStream_t stream)
{
    (void)in_sizes; (void)n_in; (void)out_size; (void)ws_size;
    PrepArgs a;
    a.qp   = (const float*)d_in[0];
    a.pf   = (const float*)d_in[1];
    a.adj  = (const float*)d_in[2];
    a.Brff = (const float*)d_in[3];
    a.v0 = (const float*)d_in[4];  a.g0 = (const float*)d_in[5];  a.b0 = (const float*)d_in[6];
    a.v1 = (const float*)d_in[7];  a.g1 = (const float*)d_in[8];  a.b1 = (const float*)d_in[9];
    a.v2 = (const float*)d_in[10]; a.g2 = (const float*)d_in[11]; a.b2 = (const float*)d_in[12];
    a.v3 = (const float*)d_in[13]; a.g3 = (const float*)d_in[14]; a.b3 = (const float*)d_in[15];
    a.v4 = (const float*)d_in[16]; a.g4 = (const float*)d_in[17]; a.b4 = (const float*)d_in[18];
    float* out = (float*)d_out;

    char* ws = (char*)d_ws;
    size_t off = 0;
    auto alloc = [&](size_t n) -> void* {
        off = (off + 255) & ~(size_t)255;
        void* p = ws + off;
        off += n;
        return p;
    };
    a.w0 = (unsigned short*)alloc(80ull * 512 * 512 * 2);
    a.w1 = (unsigned short*)alloc(80ull * 256 * 512 * 2);
    a.w2 = (unsigned short*)alloc(80ull * 128 * 256 * 2);
    a.w3 = (unsigned short*)alloc(80ull * 64 * 128 * 2);
    a.w4 = (float*)alloc(80ull * 6 * 64 * 4);
    a.bias0 = (float*)alloc(80ull * 512 * 4);
    a.bias1 = (float*)alloc(80ull * 256 * 4);
    a.bias2 = (float*)alloc(80ull * 128 * 4);
    a.bias3 = (float*)alloc(80ull * 64 * 4);
    a.bias4 = (float*)alloc(80ull * 6 * 4);
    unsigned short* hA = (unsigned short*)alloc(163840ull * 512 * 2);
    unsigned short* hB = (unsigned short*)alloc(163840ull * 512 * 2);
    a.h0 = hA;

    prep_rff_kernel<<<60280, 256, 0, stream>>>(a);
    gemm_layer_kernel<512, 512, 128, 128><<<5120, 256, 0, stream>>>(hA, a.w0, a.bias0, hB);
    gemm_layer_kernel<512, 256, 128, 128><<<2560, 256, 0, stream>>>(hB, a.w1, a.bias1, hA);
    gemm_layer_kernel<256, 128, 128, 128><<<1280, 256, 0, stream>>>(hA, a.w2, a.bias2, hB);
    gemm_tail_kernel<<<1280, 256, 0, stream>>>(hB, a.w3, a.bias3, a.w4, a.bias4, out);
}

// Round 4
// 373.319 us; speedup vs baseline: 1.3332x; 1.0087x over previous
//
#include <hip/hip_runtime.h>
#include <hip/hip_fp16.h>

#define DI __device__ __forceinline__

typedef __attribute__((ext_vector_type(4))) float f32x4;
typedef __attribute__((ext_vector_type(8))) short s16x8;

DI unsigned short f2h(float f) { return __half_as_ushort(__float2half(f)); }
DI float h2f(unsigned short u) { return __half2float(__ushort_as_half(u)); }

DI void gload16(const void* g, void* l) {
    __builtin_amdgcn_global_load_lds((const __attribute__((address_space(1))) void*)g,
                                     (__attribute__((address_space(3))) void*)l, 16, 0, 0);
}

// ---------------------------------------------------------------------------
// Fused prep (weight-norm fold + scale fold) + RFF encode, one mega-launch.
// ---------------------------------------------------------------------------
struct PrepArgs {
    const float *qp, *pf, *adj, *Brff;
    const float *v0, *g0, *b0, *v1, *g1, *b1, *v2, *g2, *b2, *v3, *g3, *b3, *v4, *g4, *b4;
    unsigned short *w0, *w1, *w2, *w3;
    float *w4;
    float *bias0, *bias1, *bias2, *bias3, *bias4;
    unsigned short *h0;
};

template <int CIN, int CINPAD>
DI void prep_row(const float* __restrict__ v, const float* __restrict__ g,
                 const float* __restrict__ b, const float* __restrict__ adj,
                 int cout, int use_scale,
                 unsigned short* __restrict__ wout, float* __restrict__ biasout,
                 int ridx, int lane)
{
    const int k = ridx / cout;
    const float* vr = v + (size_t)ridx * CIN;
    constexpr int NV = CINPAD / 64;
    float xv[NV];
    #pragma unroll
    for (int i = 0; i < NV; i++) {
        const int idx = lane + i * 64;
        xv[i] = (CIN == CINPAD || idx < CIN) ? vr[idx] : 0.f;
    }
    float ss = 0.f;
    #pragma unroll
    for (int i = 0; i < NV; i++) ss += xv[i] * xv[i];
    #pragma unroll
    for (int off = 32; off >= 1; off >>= 1) ss += __shfl_xor(ss, off, 64);
    float s = g[ridx] / sqrtf(ss);
    float bias = b[ridx];
    if (use_scale) {
        float d = adj[k * 81];            // adj[k][k]
        d = d > 0.f ? d : 0.f;
        s *= d; bias *= d;                // leaky(z)*s == leaky(z*s), s>=0
    }
    if (lane == 0) biasout[ridx] = bias;
    unsigned short* wr = wout + (size_t)ridx * CINPAD;
    #pragma unroll
    for (int i = 0; i < NV; i++) wr[lane + i * 64] = f2h(xv[i] * s);
}

DI void prep_w4_row(const float* __restrict__ v, const float* __restrict__ g,
                    const float* __restrict__ b, float* __restrict__ wout,
                    float* __restrict__ biasout, int ridx, int lane)
{
    const float x = v[(size_t)ridx * 64 + lane];
    float ss = x * x;
    #pragma unroll
    for (int off = 32; off >= 1; off >>= 1) ss += __shfl_xor(ss, off, 64);
    const float s = g[ridx] / sqrtf(ss);
    if (lane == 0) biasout[ridx] = b[ridx];
    wout[(size_t)ridx * 64 + lane] = x * s;
}

DI void rff_row(const float* __restrict__ qp, const float* __restrict__ pf,
                const float* __restrict__ Brff, unsigned short* __restrict__ h0,
                int row, int lane)
{
    const int c0 = lane * 8;
    const int bb = row / 80;
    const int kj = row - bb * 80;
    unsigned short o[8];
    if (c0 < 480) {
        const float q0 = qp[row * 3 + 0], q1 = qp[row * 3 + 1], q2 = qp[row * 3 + 2];
        float pv[8];
        *reinterpret_cast<float4*>(&pv[0]) = *reinterpret_cast<const float4*>(&pf[(size_t)row * 480 + c0]);
        *reinterpret_cast<float4*>(&pv[4]) = *reinterpret_cast<const float4*>(&pf[(size_t)row * 480 + c0 + 4]);
        const bool issin = (c0 >= 240);
        const int j0 = issin ? (c0 - 240) : c0;
        #pragma unroll
        for (int e = 0; e < 8; e++) {
            const int j = j0 + e;
            float rev = q0 * Brff[j] + q1 * Brff[240 + j] + q2 * Brff[480 + j];
            rev -= floorf(rev);           // v_sin/v_cos take revolutions
            float t = issin ? __builtin_amdgcn_sinf(rev) : __builtin_amdgcn_cosf(rev);
            o[e] = f2h(pv[e] + t);
        }
    } else {
        #pragma unroll
        for (int e = 0; e < 8; e++) o[e] = 0;
    }
    *reinterpret_cast<s16x8*>(&h0[((size_t)kj * 2048 + bb) * 512 + c0]) =
        *reinterpret_cast<const s16x8*>(o);
}

__global__ __launch_bounds__(256) void prep_rff_kernel(PrepArgs a)
{
    const int bid  = blockIdx.x;
    const int wave = threadIdx.x >> 6, lane = threadIdx.x & 63;
    if (bid < 10240)      prep_row<480, 512>(a.v0, a.g0, a.b0, a.adj, 512, 1, a.w0, a.bias0, bid * 4 + wave, lane);
    else if (bid < 15360) prep_row<512, 512>(a.v1, a.g1, a.b1, a.adj, 256, 1, a.w1, a.bias1, (bid - 10240) * 4 + wave, lane);
    else if (bid < 17920) prep_row<256, 256>(a.v2, a.g2, a.b2, a.adj, 128, 1, a.w2, a.bias2, (bid - 15360) * 4 + wave, lane);
    else if (bid < 19200) prep_row<128, 128>(a.v3, a.g3, a.b3, a.adj,  64, 0, a.w3, a.bias3, (bid - 17920) * 4 + wave, lane);
    else if (bid < 19320) prep_w4_row(a.v4, a.g4, a.b4, a.w4, a.bias4, (bid - 19200) * 4 + wave, lane);
    else                  rff_row(a.qp, a.pf, a.Brff, a.h0, (bid - 19320) * 4 + wave, lane);
}

// ---------------------------------------------------------------------------
// 8-phase 256x256 per-joint GEMM (T2 swizzle + T3/T4 counted vmcnt + T5).
// 512 threads (8 waves, 2Mx4N), BK=64, 128 KiB dynamic LDS (2 dbuf x A,B).
// Wave C = two 64-row strips (mh*128 + wm*64) x two 32-col strips
// (nh*128 + wn*32): phase quadrant (mh,nh) reads exactly A-half(mh)+B-half(nh).
// ---------------------------------------------------------------------------
DI s16x8 frag(const unsigned short* ldsT, int row, int c) {
    const int sc = c ^ (row & 7);
    return *reinterpret_cast<const s16x8*>(&ldsT[row * 64 + sc * 8]);
}

DI void stage_half(const unsigned short* g, unsigned short* l, int cin, int tid) {
    const int w = tid >> 6, lane = tid & 63;
    #pragma unroll
    for (int i = 0; i < 2; i++) {
        const int cl = (w * 2 + i) * 64 + lane;     // chunk 0..1023 of the half-tile
        const int row = cl >> 3, cc = cl & 7;
        const int sc = cc ^ (row & 7);              // inverse-swizzled global source
        gload16(g + (size_t)row * cin + sc * 8, l + (w * 2 + i) * 512);
    }
}

#define VM8 asm volatile("s_waitcnt vmcnt(8)" ::: "memory")
#define VM4 asm volatile("s_waitcnt vmcnt(4)" ::: "memory")
#define VM2 asm volatile("s_waitcnt vmcnt(2)" ::: "memory")
#define VM0 asm volatile("s_waitcnt vmcnt(0)" ::: "memory")
#define NOWAIT (void)0

template <int CIN, int COUT>
__global__ __launch_bounds__(512, 2) void gemm8p_kernel(
    const unsigned short* __restrict__ X, const unsigned short* __restrict__ W,
    const float* __restrict__ Bias, unsigned short* __restrict__ Y)
{
    constexpr int NKT = CIN / 64;            // 8 for CIN=512
    constexpr int NT = COUT / 256;
    constexpr int NWG = 8 * NT * 80;
    extern __shared__ __align__(16) unsigned short smem[];
    unsigned short* ldsA = smem;             // [buf][256][64]
    unsigned short* ldsB = smem + 32768;
    const int tid = threadIdx.x;
    const int wid = tid >> 6, lane = tid & 63;
    const int wm = wid >> 2, wn = wid & 3;
    const int l15 = lane & 15, l4 = lane >> 4;
    const int bid = blockIdx.x;
    const int swz = (bid & 7) * (NWG >> 3) + (bid >> 3);   // NWG % 8 == 0
    const int nt = swz % NT;
    const int mt = (swz / NT) & 7;
    const int kj = swz / (NT * 8);
    const int m0 = mt * 256, n0 = nt * 256;
    const unsigned short* Ab = X + (size_t)kj * 2048 * CIN + (size_t)m0 * CIN;
    const unsigned short* Bb = W + (size_t)kj * COUT * CIN + (size_t)n0 * CIN;
    f32x4 acc[8][4] = {};

#define STG_A(T, HALF) stage_half(Ab + (size_t)((HALF) * 128) * CIN + (T) * 64, \
                                  ldsA + ((T) & 1) * 16384 + (HALF) * 8192, CIN, tid)
#define STG_B(T, HALF) stage_half(Bb + (size_t)((HALF) * 128) * CIN + (T) * 64, \
                                  ldsB + ((T) & 1) * 16384 + (HALF) * 8192, CIN, tid)

#define PHASE(WAITSTMT, MH, NH, BUF, STAGESTMT) do {                              \
    WAITSTMT;                                                                     \
    __builtin_amdgcn_s_barrier();                                                 \
    s16x8 af[4][2], bf[2][2];                                                     \
    const unsigned short* pA = ldsA + (BUF) * 16384;                              \
    const unsigned short* pB = ldsB + (BUF) * 16384;                              \
    _Pragma("unroll") for (int f = 0; f < 4; f++) {                               \
        _Pragma("unroll") for (int kk = 0; kk < 2; kk++)                          \
            af[f][kk] = frag(pA, (MH) * 128 + wm * 64 + f * 16 + l15, kk * 4 + l4); } \
    _Pragma("unroll") for (int g = 0; g < 2; g++) {                               \
        _Pragma("unroll") for (int kk = 0; kk < 2; kk++)                          \
            bf[g][kk] = frag(pB, (NH) * 128 + wn * 32 + g * 16 + l15, kk * 4 + l4); } \
    STAGESTMT;                                                                    \
    asm volatile("s_waitcnt lgkmcnt(0)" ::: "memory");                            \
    __builtin_amdgcn_sched_barrier(0);                                            \
    __builtin_amdgcn_s_setprio(1);                                                \
    _Pragma("unroll") for (int kk = 0; kk < 2; kk++)                              \
        _Pragma("unroll") for (int f = 0; f < 4; f++)                             \
            _Pragma("unroll") for (int g = 0; g < 2; g++)                         \
                asm("v_mfma_f32_16x16x32_f16 %0, %1, %2, %0"                      \
                    : "+v"(acc[(MH) * 4 + f][(NH) * 2 + g])                       \
                    : "v"(af[f][kk]), "v"(bf[g][kk]));                            \
    __builtin_amdgcn_s_setprio(0);                                                \
    __builtin_amdgcn_s_barrier();                                                 \
} while (0)

    // Prologue: K-tile 0 fully + first two halves of K-tile 1 (12 gloads).
    STG_A(0, 0); STG_B(0, 0); STG_B(0, 1); STG_A(0, 1); STG_A(1, 0); STG_B(1, 0);

    // Steady iterations: compute K-tiles s (buf0) then s+1 (buf1).
    for (int s = 0; s + 2 < NKT; s += 2) {
        PHASE(VM8,    0, 0, 0, STG_B(s + 1, 1));
        PHASE(VM8,    0, 1, 0, STG_A(s + 1, 1));
        PHASE(VM8,    1, 0, 0, STG_A(s + 2, 0));
        PHASE(NOWAIT, 1, 1, 0, STG_B(s + 2, 0));
        PHASE(VM8,    0, 0, 1, STG_B(s + 2, 1));
        PHASE(VM8,    0, 1, 1, STG_A(s + 2, 1));
        PHASE(VM8,    1, 0, 1, STG_A(s + 3, 0));
        PHASE(NOWAIT, 1, 1, 1, STG_B(s + 3, 0));
    }
    // Tail iteration: s = NKT-2 (stages only the two remaining halves of NKT-1).
    PHASE(VM8,    0, 0, 0, STG_B(NKT - 1, 1));
    PHASE(VM8,    0, 1, 0, STG_A(NKT - 1, 1));
    PHASE(VM8,    1, 0, 0, NOWAIT);
    PHASE(NOWAIT, 1, 1, 0, NOWAIT);
    PHASE(VM4,    0, 0, 1, NOWAIT);
    PHASE(VM2,    0, 1, 1, NOWAIT);
    PHASE(VM0,    1, 0, 1, NOWAIT);
    PHASE(NOWAIT, 1, 1, 1, NOWAIT);

#undef PHASE
#undef STG_A
#undef STG_B

    asm volatile("s_nop 7\n\ts_nop 7" :::);   // MFMA->VALU hazard cover
    #pragma unroll
    for (int mh = 0; mh < 2; mh++)
    #pragma unroll
    for (int f = 0; f < 4; f++)
    #pragma unroll
    for (int nh = 0; nh < 2; nh++)
    #pragma unroll
    for (int g = 0; g < 2; g++) {
        const int n = n0 + nh * 128 + wn * 32 + g * 16 + l15;
        const float bias = Bias[kj * COUT + n];
        #pragma unroll
        for (int r = 0; r < 4; r++) {
            const int m = m0 + mh * 128 + wm * 64 + f * 16 + l4 * 4 + r;
            float z = acc[mh * 4 + f][nh * 2 + g][r] + bias;
            z = (z >= 0.f) ? z : 0.01f * z;
            Y[((size_t)kj * 2048 + m) * COUT + n] = f2h(z);
        }
    }
}

// ---------------------------------------------------------------------------
// 128x128 m97-style GEMM (kept for layer 2, N=128).
// ---------------------------------------------------------------------------
template <int CIN, int COUT, int BM, int BN>
__global__ __launch_bounds__(256) void gemm_layer_kernel(
    const unsigned short* __restrict__ X, const unsigned short* __restrict__ W,
    const float* __restrict__ Bias, unsigned short* __restrict__ Y)
{
    constexpr int BK = 64;
    constexpr int MT = 2048 / BM, NT = COUT / BN;
    constexpr int NWG = MT * NT * 80;
    const int bid = blockIdx.x;
    const int swz = (bid & 7) * (NWG >> 3) + (bid >> 3);
    const int nt = swz % NT;
    const int mt = (swz / NT) % MT;
    const int kj = swz / (NT * MT);
    constexpr int WR = 2, WC = 2;
    constexpr int WM = BM / WR, WN = BN / WC;
    constexpr int FM = WM / 16, FN = WN / 16;
    __shared__ __align__(16) unsigned short sA[BM * BK];
    __shared__ __align__(16) unsigned short sB[BN * BK];
    const int tid = threadIdx.x, wave = tid >> 6, lane = tid & 63;
    const int m0 = mt * BM, n0 = nt * BN;
    const unsigned short* Ab = X + (size_t)kj * 2048 * CIN;
    const unsigned short* Bb = W + (size_t)kj * COUT * CIN;
    const int wr = wave >> 1, wc = wave & 1;
    f32x4 acc[FM][FN] = {};
    constexpr int APW = (BM * 8) / 256;
    constexpr int BPW = (BN * 8) / 256;

    for (int kt = 0; kt < CIN / BK; ++kt) {
        #pragma unroll
        for (int i = 0; i < APW; i++) {
            const int cbase = (wave * APW + i) * 64;
            const int chunk = cbase + lane;
            const int row = chunk >> 3, cc = chunk & 7;
            const int sc = cc ^ (row & 7);
            gload16(Ab + (size_t)(m0 + row) * CIN + kt * BK + sc * 8,
                    sA + (size_t)cbase * 8);
        }
        #pragma unroll
        for (int i = 0; i < BPW; i++) {
            const int cbase = (wave * BPW + i) * 64;
            const int chunk = cbase + lane;
            const int row = chunk >> 3, cc = chunk & 7;
            const int sc = cc ^ (row & 7);
            gload16(Bb + (size_t)(n0 + row) * CIN + kt * BK + sc * 8,
                    sB + (size_t)cbase * 8);
        }
        __syncthreads();
        #pragma unroll
        for (int kk = 0; kk < 2; kk++) {
            s16x8 af[FM], bf[FN];
            #pragma unroll
            for (int mf = 0; mf < FM; mf++) {
                const int row = wr * WM + mf * 16 + (lane & 15);
                const int c   = kk * 4 + (lane >> 4);
                const int sc2 = c ^ (row & 7);
                af[mf] = *reinterpret_cast<const s16x8*>(&sA[row * BK + sc2 * 8]);
            }
            #pragma unroll
            for (int nf = 0; nf < FN; nf++) {
                const int row = wc * WN + nf * 16 + (lane & 15);
                const int c   = kk * 4 + (lane >> 4);
                const int sc2 = c ^ (row & 7);
                bf[nf] = *reinterpret_cast<const s16x8*>(&sB[row * BK + sc2 * 8]);
            }
            #pragma unroll
            for (int mf = 0; mf < FM; mf++)
                #pragma unroll
                for (int nf = 0; nf < FN; nf++)
                    asm("v_mfma_f32_16x16x32_f16 %0, %1, %2, %0"
                        : "+v"(acc[mf][nf]) : "v"(af[mf]), "v"(bf[nf]));
        }
        __syncthreads();
    }
    asm volatile("s_nop 7\n\ts_nop 7" :::);
    #pragma unroll
    for (int nf = 0; nf < FN; nf++) {
        const int n = n0 + wc * WN + nf * 16 + (lane & 15);
        const float bias = Bias[kj * COUT + n];
        #pragma unroll
        for (int mf = 0; mf < FM; mf++) {
            #pragma unroll
            for (int r = 0; r < 4; r++) {
                const int m = m0 + wr * WM + mf * 16 + (lane >> 4) * 4 + r;
                float z = acc[mf][nf][r] + bias;
                z = (z >= 0.f) ? z : 0.01f * z;
                Y[((size_t)kj * 2048 + m) * COUT + n] = f2h(z);
            }
        }
    }
}

// ---------------------------------------------------------------------------
// Tail: layer-3 GEMM (128->64) with fused layer-4 (64->6) and output store.
// ---------------------------------------------------------------------------
__global__ __launch_bounds__(256) void gemm_tail_kernel(
    const unsigned short* __restrict__ X, const unsigned short* __restrict__ W,
    const float* __restrict__ Bias, const float* __restrict__ W4,
    const float* __restrict__ B4, float* __restrict__ out)
{
    constexpr int CIN = 128, COUT = 64, BM = 128, BN = 64, BK = 64;
    constexpr int MT = 16, NWG = MT * 80;
    __shared__ __align__(16) unsigned short sA[BM * BK];   // reused as h4 tile
    __shared__ __align__(16) unsigned short sB[BN * BK];
    __shared__ float sW4[6 * 64];
    __shared__ float sB4[6];
    const int tid = threadIdx.x, wave = tid >> 6, lane = tid & 63;
    const int bid = blockIdx.x;
    const int swz = (bid & 7) * (NWG >> 3) + (bid >> 3);
    const int mt = swz & (MT - 1);
    const int kj = swz >> 4;
    const int m0 = mt * BM;
    for (int i = tid; i < 390; i += 256) {
        if (i < 384) sW4[i] = W4[kj * 384 + i];
        else         sB4[i - 384] = B4[kj * 6 + (i - 384)];
    }
    const unsigned short* Ab = X + (size_t)kj * 2048 * CIN;
    const unsigned short* Bb = W + (size_t)kj * COUT * CIN;
    const int wr = wave >> 1, wc = wave & 1;
    constexpr int WM = 64, WN = 32, FM = 4, FN = 2;
    f32x4 acc[FM][FN] = {};
    constexpr int APW = (BM * 8) / 256;   // 4
    constexpr int BPW = (BN * 8) / 256;   // 2

    for (int kt = 0; kt < CIN / BK; ++kt) {
        #pragma unroll
        for (int i = 0; i < APW; i++) {
            const int cbase = (wave * APW + i) * 64;
            const int chunk = cbase + lane;
            const int row = chunk >> 3, cc = chunk & 7;
            const int sc = cc ^ (row & 7);
            gload16(Ab + (size_t)(m0 + row) * CIN + kt * BK + sc * 8,
                    sA + (size_t)cbase * 8);
        }
        #pragma unroll
        for (int i = 0; i < BPW; i++) {
            const int cbase = (wave * BPW + i) * 64;
            const int chunk = cbase + lane;
            const int row = chunk >> 3, cc = chunk & 7;
            const int sc = cc ^ (row & 7);
            gload16(Bb + (size_t)row * CIN + kt * BK + sc * 8,   // n0 == 0
                    sB + (size_t)cbase * 8);
        }
        __syncthreads();
        #pragma unroll
        for (int kk = 0; kk < 2; kk++) {
            s16x8 af[FM], bf[FN];
            #pragma unroll
            for (int mf = 0; mf < FM; mf++) {
                const int row = wr * WM + mf * 16 + (lane & 15);
                const int c   = kk * 4 + (lane >> 4);
                const int sc2 = c ^ (row & 7);
                af[mf] = *reinterpret_cast<const s16x8*>(&sA[row * BK + sc2 * 8]);
            }
            #pragma unroll
            for (int nf = 0; nf < FN; nf++) {
                const int row = wc * WN + nf * 16 + (lane & 15);
                const int c   = kk * 4 + (lane >> 4);
                const int sc2 = c ^ (row & 7);
                bf[nf] = *reinterpret_cast<const s16x8*>(&sB[row * BK + sc2 * 8]);
            }
            #pragma unroll
            for (int mf = 0; mf < FM; mf++)
                #pragma unroll
                for (int nf = 0; nf < FN; nf++)
                    asm("v_mfma_f32_16x16x32_f16 %0, %1, %2, %0"
                        : "+v"(acc[mf][nf]) : "v"(af[mf]), "v"(bf[nf]));
        }
        __syncthreads();
    }
    asm volatile("s_nop 7\n\ts_nop 7" :::);
    #pragma unroll
    for (int nf = 0; nf < FN; nf++) {
        const int n = wc * WN + nf * 16 + (lane & 15);
        const float bias = Bias[kj * COUT + n];
        #pragma unroll
        for (int mf = 0; mf < FM; mf++) {
            #pragma unroll
            for (int r = 0; r < 4; r++) {
                const int rl = wr * WM + mf * 16 + (lane >> 4) * 4 + r;
                float z = acc[mf][nf][r] + bias;
                z = (z >= 0.f) ? z : 0.01f * z;
                sA[rl * 64 + (((n >> 3) ^ (rl & 7)) << 3) + (n & 7)] = f2h(z);
            }
        }
    }
    __syncthreads();
    if (tid < 128) {
        const int row = tid;
        float xv[64];
        #pragma unroll
        for (int j = 0; j < 8; j++) {
            s16x8 vv = *reinterpret_cast<const s16x8*>(&sA[row * 64 + ((j ^ (row & 7)) << 3)]);
            #pragma unroll
            for (int e = 0; e < 8; e++) xv[j * 8 + e] = h2f((unsigned short)vv[e]);
        }
        float* op = out + ((size_t)(m0 + row) * 80 + kj) * 6;
        #pragma unroll
        for (int o = 0; o < 6; o++) {
            float sum = sB4[o];
            #pragma unroll
            for (int i = 0; i < 64; i++) sum = fmaf(xv[i], sW4[o * 64 + i], sum);
            op[o] = sum;
        }
    }
}

// ---------------------------------------------------------------------------
extern "C" void kernel_launch(void* const* d_in, const int* in_sizes, int n_in,
                              void* d_out, int out_size, void* d_ws, size_t ws_size,
                              hipStream_t stream)
{
    (void)in_sizes; (void)n_in; (void)out_size; (void)ws_size;
    PrepArgs a;
    a.qp   = (const float*)d_in[0];
    a.pf   = (const float*)d_in[1];
    a.adj  = (const float*)d_in[2];
    a.Brff = (const float*)d_in[3];
    a.v0 = (const float*)d_in[4];  a.g0 = (const float*)d_in[5];  a.b0 = (const float*)d_in[6];
    a.v1 = (const float*)d_in[7];  a.g1 = (const float*)d_in[8];  a.b1 = (const float*)d_in[9];
    a.v2 = (const float*)d_in[10]; a.g2 = (const float*)d_in[11]; a.b2 = (const float*)d_in[12];
    a.v3 = (const float*)d_in[13]; a.g3 = (const float*)d_in[14]; a.b3 = (const float*)d_in[15];
    a.v4 = (const float*)d_in[16]; a.g4 = (const float*)d_in[17]; a.b4 = (const float*)d_in[18];
    float* out = (float*)d_out;

    char* ws = (char*)d_ws;
    size_t off = 0;
    auto alloc = [&](size_t n) -> void* {
        off = (off + 255) & ~(size_t)255;
        void* p = ws + off;
        off += n;
        return p;
    };
    a.w0 = (unsigned short*)alloc(80ull * 512 * 512 * 2);
    a.w1 = (unsigned short*)alloc(80ull * 256 * 512 * 2);
    a.w2 = (unsigned short*)alloc(80ull * 128 * 256 * 2);
    a.w3 = (unsigned short*)alloc(80ull * 64 * 128 * 2);
    a.w4 = (float*)alloc(80ull * 6 * 64 * 4);
    a.bias0 = (float*)alloc(80ull * 512 * 4);
    a.bias1 = (float*)alloc(80ull * 256 * 4);
    a.bias2 = (float*)alloc(80ull * 128 * 4);
    a.bias3 = (float*)alloc(80ull * 64 * 4);
    a.bias4 = (float*)alloc(80ull * 6 * 4);
    unsigned short* hA = (unsigned short*)alloc(163840ull * 512 * 2);
    unsigned short* hB = (unsigned short*)alloc(163840ull * 512 * 2);
    a.h0 = hA;

    // allow 128 KiB dynamic LDS (idempotent, capture-safe: no stream work)
    (void)hipFuncSetAttribute((const void*)gemm8p_kernel<512, 512>,
                              hipFuncAttributeMaxDynamicSharedMemorySize, 131072);
    (void)hipFuncSetAttribute((const void*)gemm8p_kernel<512, 256>,
                              hipFuncAttributeMaxDynamicSharedMemorySize, 131072);

    prep_rff_kernel<<<60280, 256, 0, stream>>>(a);
    gemm8p_kernel<512, 512><<<1280, 512, 131072, stream>>>(hA, a.w0, a.bias0, hB);
    gemm8p_kernel<512, 256><<<640,  512, 131072, stream>>>(hB, a.w1, a.bias1, hA);
    gemm_layer_kernel<256, 128, 128, 128><<<1280, 256, 0, stream>>>(hA, a.w2, a.bias2, hB);
    gemm_tail_kernel<<<1280, 256, 0, stream>>>(hB, a.w3, a.bias3, a.w4, a.bias4, out);
}